// Round 2
// 678.827 us; speedup vs baseline: 1.1338x; 1.1338x over previous
//
#include <hip/hip_runtime.h>

// WKV7 recurrence, T=4096, H=32, N=64, fp32. One wave per state row.
// R7 post-mortem: latency-bound (VALUBusy 48%, HBM 2.5%, occ 24%): the two
// serial 6-stage DPP reduction chains per step (sa-reduce, x-reduce) ran
// back-to-back, each with s_nop-1 hazard gaps, and both resident waves stall
// in lockstep. R8: pair x_t-reduce with sa_{t+1}-reduce (both depend on s_t)
// in ONE interleaved DPP block — each chain's op fills the other's 2-wait-
// state DPP hazard window (X Y nop0 X Y nop0 ...). Chunk-boundary pair runs
// after the staging barrier (r held in register, a read from new buffer).
// R8b: __builtin_amdgcn_writelane not available on this ROCm — use the
// proven cndmask select for xacc instead.

static constexpr int T_LEN = 4096;
static constexpr int H_HEADS = 32;
static constexpr int N_DIM = 64;
static constexpr int HN = H_HEADS * N_DIM;                 // 2048
static constexpr int WPB = 8;                              // waves/block
static constexpr int BT = WPB * 64;                        // 512 threads
static constexpr int NB = (H_HEADS * N_DIM) / WPB;         // 256 blocks
static constexpr int C = 16;                               // steps/chunk
static constexpr int TC = T_LEN / C;                       // 256 chunks

// ---- raw buffer load: SGPR soffset, OOB-safe prefetch (returns 0) ----
typedef int int32x4_t __attribute__((ext_vector_type(4)));
__device__ float llvm_amdgcn_raw_buffer_load_fp32(int32x4_t srsrc, int voffset,
                                                  int soffset, int glc_slc)
    __asm("llvm.amdgcn.raw.buffer.load.f32");

__device__ __forceinline__ int32x4_t make_srd(const void* p, unsigned bytes) {
  int32x4_t r;
  r.x = (int)(unsigned long long)p;
  r.y = (int)((unsigned long long)p >> 32); // stride=0 -> raw
  r.z = (int)bytes;                         // num_records
  r.w = 0x00020000;                         // raw dword
  return r;
}

// ---- 64-lane sum, single chain (prologue only) ----
__device__ __forceinline__ float wave_sum_bcast(float x) {
  asm volatile(
      "s_nop 1\n\t"
      "v_add_f32 %0, %0, %0 row_shr:1 bound_ctrl:0\n\t"
      "s_nop 1\n\t"
      "v_add_f32 %0, %0, %0 row_shr:2 bound_ctrl:0\n\t"
      "s_nop 1\n\t"
      "v_add_f32 %0, %0, %0 row_shr:4 bound_ctrl:0\n\t"
      "s_nop 1\n\t"
      "v_add_f32 %0, %0, %0 row_shr:8 bound_ctrl:0\n\t"
      "s_nop 1\n\t"
      "v_add_f32 %0, %0, %0 row_bcast:15 row_mask:0xa\n\t"
      "s_nop 1\n\t"
      "v_add_f32 %0, %0, %0 row_bcast:31 row_mask:0xc\n\t"
      "s_nop 1\n\t"
      : "+v"(x));
  return __int_as_float(__builtin_amdgcn_readlane(__float_as_int(x), 63));
}

// ---- paired 64-lane sums: two independent chains interleaved so each DPP
// op (+ s_nop 0) covers the other chain's 2-wait-state DPP hazard. 12 VALU
// + 7 nops for BOTH sums, latency of ~one chain instead of two. ----
__device__ __forceinline__ void wave_sum2(float& x, float& y) {
  asm volatile(
      "s_nop 1\n\t"
      "v_add_f32 %0, %0, %0 row_shr:1 bound_ctrl:0\n\t"
      "v_add_f32 %1, %1, %1 row_shr:1 bound_ctrl:0\n\t"
      "s_nop 0\n\t"
      "v_add_f32 %0, %0, %0 row_shr:2 bound_ctrl:0\n\t"
      "v_add_f32 %1, %1, %1 row_shr:2 bound_ctrl:0\n\t"
      "s_nop 0\n\t"
      "v_add_f32 %0, %0, %0 row_shr:4 bound_ctrl:0\n\t"
      "v_add_f32 %1, %1, %1 row_shr:4 bound_ctrl:0\n\t"
      "s_nop 0\n\t"
      "v_add_f32 %0, %0, %0 row_shr:8 bound_ctrl:0\n\t"
      "v_add_f32 %1, %1, %1 row_shr:8 bound_ctrl:0\n\t"
      "s_nop 0\n\t"
      "v_add_f32 %0, %0, %0 row_bcast:15 row_mask:0xa\n\t"
      "v_add_f32 %1, %1, %1 row_bcast:15 row_mask:0xa\n\t"
      "s_nop 0\n\t"
      "v_add_f32 %0, %0, %0 row_bcast:31 row_mask:0xc\n\t"
      "v_add_f32 %1, %1, %1 row_bcast:31 row_mask:0xc\n\t"
      "s_nop 1\n\t"
      : "+v"(x), "+v"(y));
}

__global__ __launch_bounds__(BT, 2) void wkv7_scan(
    const float* __restrict__ rp, const float* __restrict__ wp,
    const float* __restrict__ kp, const float* __restrict__ vp,
    const float* __restrict__ ap, const float* __restrict__ bp,
    const float* __restrict__ s0p, float* __restrict__ xp,
    float* __restrict__ sop) {
  const int tid  = threadIdx.x;
  const int lane = tid & 63;
  const int wv   = tid >> 6;
  const int blk  = blockIdx.x;
  const int h     = blk & (H_HEADS - 1);
  const int ibase = (blk >> 5) * WPB;
  const int i     = ibase + wv;
  const int hb    = h * N_DIM;

  // [buf][step][channel]: read addr = lane*4 + imm -> conflict-free
  __shared__ float sw[2][C][N_DIM], sA[2][C][N_DIM], sB[2][C][N_DIM],
                   sK[2][C][N_DIM], sR[2][C][N_DIM];
  __shared__ float sV[2][C][WPB];
  __shared__ float xbuf[WPB][65];

  constexpr unsigned ARR_BYTES = (unsigned)T_LEN * HN * 4u;
  const int32x4_t srd_r = make_srd(rp, ARR_BYTES);
  const int32x4_t srd_w = make_srd(wp, ARR_BYTES);
  const int32x4_t srd_k = make_srd(kp, ARR_BYTES);
  const int32x4_t srd_v = make_srd(vp, ARR_BYTES);
  const int32x4_t srd_a = make_srd(ap, ARR_BYTES);
  const int32x4_t srd_b = make_srd(bp, ARR_BYTES);

  float s = s0p[(size_t)(hb + i) * N_DIM + lane];

  // staging index map: thread covers (u0, j) and (u0+8, j) for 5 arrays
  const int j   = lane;
  const int u0  = tid >> 6;                       // 0..7
  const int vo0 = (u0 * HN + j) << 2;             // pass 0 voffset (bytes)
  const int vo1 = vo0 + (8 * HN << 2);            // pass 1
  const int sbase = hb << 2;
  // v staging: waves 0-1 (tid<128): u=tid>>3 (0..15), q=tid&7
  const int uv  = tid >> 3;
  const int qv  = tid & 7;
  const int vov = (uv * HN + qv) << 2;
  const int svbase = (hb + ibase) << 2;

  float g0, g1, g2, g3, g4, g5, g6, g7, g8, g9, g10;

#define STAGE_LOAD(CI)                                                   \
  do {                                                                   \
    const int so = (CI) * (C * HN * 4) + sbase;                          \
    g0 = llvm_amdgcn_raw_buffer_load_fp32(srd_w, vo0, so, 0);            \
    g1 = llvm_amdgcn_raw_buffer_load_fp32(srd_a, vo0, so, 0);            \
    g2 = llvm_amdgcn_raw_buffer_load_fp32(srd_b, vo0, so, 0);            \
    g3 = llvm_amdgcn_raw_buffer_load_fp32(srd_k, vo0, so, 0);            \
    g4 = llvm_amdgcn_raw_buffer_load_fp32(srd_r, vo0, so, 0);            \
    g5 = llvm_amdgcn_raw_buffer_load_fp32(srd_w, vo1, so, 0);            \
    g6 = llvm_amdgcn_raw_buffer_load_fp32(srd_a, vo1, so, 0);            \
    g7 = llvm_amdgcn_raw_buffer_load_fp32(srd_b, vo1, so, 0);            \
    g8 = llvm_amdgcn_raw_buffer_load_fp32(srd_k, vo1, so, 0);            \
    g9 = llvm_amdgcn_raw_buffer_load_fp32(srd_r, vo1, so, 0);            \
    if (wv < 2)                                                          \
      g10 = llvm_amdgcn_raw_buffer_load_fp32(                            \
          srd_v, vov, (CI) * (C * HN * 4) + svbase, 0);                  \
  } while (0)

#define STAGE_STORE(BI)                                                  \
  do {                                                                   \
    sw[BI][u0][j] = g0;  sA[BI][u0][j] = g1;  sB[BI][u0][j] = g2;        \
    sK[BI][u0][j] = g3;  sR[BI][u0][j] = g4;                             \
    sw[BI][u0 + 8][j] = g5;  sA[BI][u0 + 8][j] = g6;                     \
    sB[BI][u0 + 8][j] = g7;  sK[BI][u0 + 8][j] = g8;                     \
    sR[BI][u0 + 8][j] = g9;                                              \
    if (wv < 2) sV[BI][uv][qv] = g10;                                    \
  } while (0)

  float xacc = 0.0f;

  STAGE_LOAD(0);
  STAGE_STORE(0);
  __syncthreads();

  // prologue: sa for step 0 (only unpaired reduction in the whole kernel)
  float sa;
  {
    float p0 = s * sA[0][0][lane];
    sa = wave_sum_bcast(p0);
  }

  for (int c = 0; c < TC; ++c) {
    const int bi = c & 1;

    STAGE_LOAD(c + 1);              // global loads fly under compute
    __builtin_amdgcn_sched_barrier(0);

    // one-step LDS prefetch; la1 tracks a of step u+1 (pair partner)
    float lw = sw[bi][0][lane], lb = sB[bi][0][lane], lk = sK[bi][0][lane],
          lr = sR[bi][0][lane], lv = sV[bi][0][wv];
    float la1 = sA[bi][1][lane];
    float lr15 = 0.0f;
#pragma unroll
    for (int u = 0; u < C; ++u) {
      const int un = (u < C - 1) ? u + 1 : u;  // compile-time per iter
      const float nw = sw[bi][un][lane], nb = sB[bi][un][lane],
                  nk = sK[bi][un][lane], nr = sR[bi][un][lane],
                  nv = sV[bi][un][wv];
      const float na = (u < C - 2) ? sA[bi][u + 2][lane] : 0.0f;

      // update step t = c*16+u (sa_t already computed by previous pair)
      s = fmaf(s, lw, fmaf(sa, lb, lv * lk));

      if (u < C - 1) {
        // paired: x_t = sum(s_t*r_t) with sa_{t+1} = sum(s_t*a_{t+1})
        float px = s * lr, pa = s * la1;
        wave_sum2(px, pa);
        const float xv =
            __int_as_float(__builtin_amdgcn_readlane(__float_as_int(px), 63));
        sa = __int_as_float(__builtin_amdgcn_readlane(__float_as_int(pa), 63));
        const int tl = ((c & 3) << 4) | u;
        xacc = (lane == tl) ? xv : xacc;
      } else {
        lr15 = lr;                  // r of chunk-last step, pair after barrier
      }

      lw = nw; lb = nb; lk = nk; lr = nr; lv = nv; la1 = na;
    }

    __builtin_amdgcn_sched_barrier(0);
    STAGE_STORE(bi ^ 1);            // vmcnt wait lands here, after compute
    __syncthreads();

    // boundary pair: x_{c*16+15} with sa of next chunk's step 0.
    // Old buffer bi is intact (we staged into bi^1); a_{t+1} now in bi^1.
    // Last chunk: staged data is OOB-zeros -> sa=0, dead after loop exit.
    {
      float la0 = sA[bi ^ 1][0][lane];
      float px = s * lr15, pa = s * la0;
      wave_sum2(px, pa);
      const float xv =
          __int_as_float(__builtin_amdgcn_readlane(__float_as_int(px), 63));
      sa = __int_as_float(__builtin_amdgcn_readlane(__float_as_int(pa), 63));
      const int tl = ((c & 3) << 4) | 15;
      xacc = (lane == tl) ? xv : xacc;
    }

    if ((c & 3) == 3) {
      // 64 steps complete: transpose through LDS -> coalesced stores
      xbuf[wv][lane] = xacc;
      __syncthreads();
      const int tl2 = tid >> 3;
      const int iw  = tid & 7;
      const int t0  = (c + 1) * C - 64;
      xp[(size_t)(t0 + tl2) * HN + hb + ibase + iw] = xbuf[iw][tl2];
      // no trailing barrier needed: next xbuf write is 4 chunk-barriers away
    }
  }

#undef STAGE_LOAD
#undef STAGE_STORE

  sop[(size_t)(hb + i) * N_DIM + lane] = s;
}

extern "C" void kernel_launch(void* const* d_in, const int* in_sizes, int n_in,
                              void* d_out, int out_size, void* d_ws, size_t ws_size,
                              hipStream_t stream) {
  // setup_inputs order: seq_length(int,1), r, w, k, v, a, b, state2
  const float* r  = (const float*)d_in[1];
  const float* w  = (const float*)d_in[2];
  const float* k  = (const float*)d_in[3];
  const float* v  = (const float*)d_in[4];
  const float* a  = (const float*)d_in[5];
  const float* b  = (const float*)d_in[6];
  const float* s0 = (const float*)d_in[7];
  float* x    = (float*)d_out;                       // [T,H,1,N] flat
  float* sout = x + (size_t)T_LEN * H_HEADS * N_DIM; // [H,N,N]

  wkv7_scan<<<dim3(NB), dim3(BT), 0, stream>>>(r, w, k, v, a, b, s0, x, sout);
}